// Round 9
// baseline (179.578 us; speedup 1.0000x reference)
//
#include <hip/hip_runtime.h>
#include <stdint.h>

// Problem constants
#define T_LEN 2048
#define C_DIM 1024
#define NHEAD 16
#define HDIM  64
#define MTOT  4096   // B*T

typedef __bf16 bf16;
typedef __bf16 bf16x4 __attribute__((ext_vector_type(4)));
typedef __bf16 bf16x8 __attribute__((ext_vector_type(8)));
typedef float  f32x4  __attribute__((ext_vector_type(4)));

__device__ __forceinline__ bf16 f2bf(float f) {
    union { float f; unsigned u; } x; x.f = f;
    unsigned r = x.u + 0x7fffu + ((x.u >> 16) & 1u);
    unsigned short h = (unsigned short)(r >> 16);
    return __builtin_bit_cast(bf16, h);
}

// async 16B/lane global -> LDS DMA (m97 pattern). LDS dest linear in lane id.
__device__ __forceinline__ void g2l16(const void* g, const void* l) {
    __builtin_amdgcn_global_load_lds(
        (const __attribute__((address_space(1))) unsigned int*)(uintptr_t)g,
        (__attribute__((address_space(3))) unsigned int*)(uint32_t)(uintptr_t)l,
        16, 0, 0);
}

// ---------------- merged prep: cast x (blocks 0..2047) + transpose/cast W (2048..3071) ----------------
__global__ void cast_xw_kernel(const float* __restrict__ x, bf16* __restrict__ xb,
                               const float* __restrict__ W0, const float* __restrict__ W1,
                               const float* __restrict__ W2, const float* __restrict__ W3,
                               bf16* __restrict__ wt) {
    __shared__ float tile[64][68];
    const int tid = threadIdx.x;
    const int bid = blockIdx.x;
    if (bid < 2048) {
        int f = bid * 256 + tid;                 // 8 bf16 elems each
        const float4* p = (const float4*)x + (size_t)f * 2;
        float4 a = p[0], b = p[1];
        bf16x8 o;
        o[0] = f2bf(a.x); o[1] = f2bf(a.y); o[2] = f2bf(a.z); o[3] = f2bf(a.w);
        o[4] = f2bf(b.x); o[5] = f2bf(b.y); o[6] = f2bf(b.z); o[7] = f2bf(b.w);
        ((bf16x8*)xb)[f] = o;
        return;
    }
    const int i = bid - 2048;                    // 0..1023
    const int w = i >> 8;
    const int nt = (i >> 4) & 15;
    const int kt = i & 15;
    const float* W = (w == 0) ? W0 : (w == 1) ? W1 : (w == 2) ? W2 : W3;
    const int kb = kt * 64, nb = nt * 64;
#pragma unroll
    for (int pass = 0; pass < 4; ++pass) {
        int row = pass * 16 + (tid >> 4);
        int col = (tid & 15) * 4;
        float4 v = *(const float4*)(W + (size_t)(kb + row) * 1024 + nb + col);
        *(float4*)(&tile[row][col]) = v;
    }
    __syncthreads();
#pragma unroll
    for (int pass = 0; pass < 2; ++pass) {
        int s = pass * 256 + tid;
        int nn = s >> 3, c = s & 7;
        bf16x8 o;
#pragma unroll
        for (int j = 0; j < 8; ++j) o[j] = f2bf(tile[c * 8 + j][nn]);
        *(bf16x8*)(wt + (size_t)w * 1048576 + (size_t)(nb + nn) * 1024 + kb + c * 8) = o;
    }
}

// V[bh][t][d] -> Vtp[bh][d][PV-permuted t]. Within each 32-key chunk,
// PV position matches the S^T C-layout -> PV B-fragment register identity.
__global__ void transpose_v_kernel(const bf16* __restrict__ V, bf16* __restrict__ Vtp) {
    __shared__ bf16 tile[128][72];   // 144B rows (16B-aligned)
    const int tid = threadIdx.x;
    const int t0 = blockIdx.x * 128, bh = blockIdx.y;
    const size_t hb = (size_t)bh * 131072;
#pragma unroll
    for (int pass = 0; pass < 4; ++pass) {
        int s = pass * 256 + tid;
        int row = s >> 3, c = s & 7;             // t-row, d-chunk
        bf16x8 v = *(const bf16x8*)(V + hb + (size_t)(t0 + row) * 64 + c * 8);
        *(bf16x8*)(&tile[row][c * 8]) = v;
    }
    __syncthreads();
#pragma unroll
    for (int pass = 0; pass < 4; ++pass) {
        int s = pass * 256 + tid;
        int d = s >> 4, ch = s & 15;             // out d row, PV-position chunk of 8
        bf16x8 o;
#pragma unroll
        for (int j = 0; j < 8; ++j) {
            int orig = 32 * (ch >> 2) + 16 * (j >> 2) + 4 * (ch & 3) + (j & 3);
            o[j] = tile[orig][d];
        }
        *(bf16x8*)(Vtp + hb + (size_t)d * 2048 + t0 + ch * 8) = o;
    }
}

// ---------------- QKV projection GEMM: 128m x 192n, BK=32, double-buffered ----------------
// 512 blocks = 2/CU (tail-free). ONE barrier per BK step; prefetch issued after
// the barrier overlaps the whole compute phase (attn-v5 pattern).
// 64B rows; conflict-free swizzle: element (row, kchunk c) stored at slot
// c ^ ((row>>1)&3); staging folds the inverse into the global source address.
__global__ __launch_bounds__(256, 2)
void gemm_qkv_kernel(const bf16* __restrict__ A, const bf16* __restrict__ Wt,
                     const float* __restrict__ b0, const float* __restrict__ b1,
                     const float* __restrict__ b2, bf16* __restrict__ outQKV) {
    __shared__ char lds[40960];
    // buf at 20480*b: As [128][32] 8KB, Bs at +8192: [192][32] 12KB

    const int tid = threadIdx.x;
    const int lane = tid & 63, wid = tid >> 6;
    const int r = lane & 15, q4 = lane >> 4;
    const int mbase = blockIdx.y * 128;
    const int nbase = blockIdx.x * 192;          // n' in [0,3072)
    const int wm = (wid >> 1) * 64;
    const int wn = (wid & 1) * 96;

    f32x4 acc[4][6];
#pragma unroll
    for (int i = 0; i < 4; ++i)
#pragma unroll
        for (int j = 0; j < 6; ++j) acc[i][j] = f32x4{0.f, 0.f, 0.f, 0.f};

    auto stage = [&](int buf, int kb) {
        char* As = lds + buf * 20480;
        char* Bs = As + 8192;
#pragma unroll
        for (int p = 0; p < 2; ++p) {
            int s = p * 256 + tid;
            int row = s >> 2, sl = s & 3;
            int c = sl ^ ((row >> 1) & 3);
            g2l16(A + (size_t)(mbase + row) * 1024 + kb + c * 8, As + s * 16);
        }
#pragma unroll
        for (int p = 0; p < 3; ++p) {
            int s = p * 256 + tid;
            int row = s >> 2, sl = s & 3;
            int c = sl ^ ((row >> 1) & 3);
            g2l16(Wt + (size_t)(nbase + row) * 1024 + kb + c * 8, Bs + s * 16);
        }
    };

    stage(0, 0);

    for (int kt = 0; kt < 32; ++kt) {
        __syncthreads();
        const int cb = kt & 1;
        if (kt < 31) stage(cb ^ 1, (kt + 1) * 32);   // overlaps compute below
        const char* As = lds + cb * 20480;
        const char* Bs = As + 8192;

        bf16x8 a[4], b[6];
#pragma unroll
        for (int i = 0; i < 4; ++i) {
            int rowa = wm + i * 16 + r;
            a[i] = *(const bf16x8*)(As + rowa * 64 + ((q4 ^ ((rowa >> 1) & 3)) * 16));
        }
#pragma unroll
        for (int j = 0; j < 6; ++j) {
            int rowb = wn + j * 16 + r;
            b[j] = *(const bf16x8*)(Bs + rowb * 64 + ((q4 ^ ((rowb >> 1) & 3)) * 16));
        }
#pragma unroll
        for (int i = 0; i < 4; ++i)
#pragma unroll
            for (int j = 0; j < 6; ++j)
                acc[i][j] = __builtin_amdgcn_mfma_f32_16x16x32_bf16(b[j], a[i], acc[i][j], 0, 0, 0);
    }

    // C^T epilogue: lane holds 4 consecutive n' for fixed m.
    const float QS = 0.18033688011112042f;       // 0.125 * log2(e)
#pragma unroll
    for (int i = 0; i < 4; ++i) {
        int m = mbase + wm + i * 16 + r;
        int bi = m >> 11, t = m & 2047;
#pragma unroll
        for (int j = 0; j < 6; ++j) {
            int n0 = nbase + wn + j * 16 + q4 * 4;   // global n' in [0,3072)
            int z = n0 >> 10;
            int nz = n0 & 1023;
            const float* bias = (z == 0) ? b0 : (z == 1) ? b1 : b2;
            float4 bb = *(const float4*)(bias + nz);
            float osc = (z == 0) ? QS : 1.0f;
            bf16x4 w;
            w[0] = f2bf((acc[i][j][0] + bb.x) * osc);
            w[1] = f2bf((acc[i][j][1] + bb.y) * osc);
            w[2] = f2bf((acc[i][j][2] + bb.z) * osc);
            w[3] = f2bf((acc[i][j][3] + bb.w) * osc);
            int h = nz >> 6, d = nz & 63;
            *(bf16x4*)(outQKV + (size_t)z * 4194304 + ((size_t)(bi * 16 + h) * 2048 + t) * 64 + d) = w;
        }
    }
}

// ---------------- output projection GEMM: 128x64, BK=64, double-buffered ----------------
// 512 blocks = 2/CU; one barrier per BK step; prefetch after barrier.
__global__ __launch_bounds__(256, 2)
void gemm_o_kernel(const bf16* __restrict__ A, const bf16* __restrict__ Bt,
                   const float* __restrict__ bias, float* __restrict__ out) {
    __shared__ char lds[49152];
    // buf at 24576*b: As [128][64] 16KB, Bs at +16384: [64][64] 8KB (128B rows, mask-7 swizzle)

    const int tid = threadIdx.x;
    const int lane = tid & 63, wid = tid >> 6;
    const int r = lane & 15, q4 = lane >> 4;
    const int nb = blockIdx.x * 64;
    const int mb = blockIdx.y * 128;
    const int wm = (wid >> 1) * 64;
    const int wn = (wid & 1) * 32;

    float4 bvv[2];
#pragma unroll
    for (int j = 0; j < 2; ++j) bvv[j] = *(const float4*)(bias + nb + wn + j * 16 + q4 * 4);

    f32x4 acc[4][2];
#pragma unroll
    for (int i = 0; i < 4; ++i)
#pragma unroll
        for (int j = 0; j < 2; ++j) acc[i][j] = f32x4{0.f, 0.f, 0.f, 0.f};

    auto stage = [&](int buf, int kb) {
        char* As = lds + buf * 24576;
        char* Bs = As + 16384;
#pragma unroll
        for (int p = 0; p < 4; ++p) {
            int s = p * 256 + tid;
            int row = s >> 3, blk = s & 7;
            g2l16(A + (size_t)(mb + row) * 1024 + kb + ((blk ^ (row & 7)) * 8), As + s * 16);
        }
#pragma unroll
        for (int p = 0; p < 2; ++p) {
            int s = p * 256 + tid;
            int row = s >> 3, blk = s & 7;
            g2l16(Bt + (size_t)(nb + row) * 1024 + kb + ((blk ^ (row & 7)) * 8), Bs + s * 16);
        }
    };

    stage(0, 0);

    for (int kt = 0; kt < 16; ++kt) {
        __syncthreads();
        const int cb = kt & 1;
        if (kt < 15) stage(cb ^ 1, (kt + 1) * 64);
        const char* As = lds + cb * 24576;
        const char* Bs = As + 16384;
#pragma unroll
        for (int ks = 0; ks < 2; ++ks) {
            int blk = ks * 4 + q4;
            bf16x8 a[4], b[2];
#pragma unroll
            for (int i = 0; i < 4; ++i) {
                int rowa = wm + i * 16 + r;
                a[i] = *(const bf16x8*)(As + rowa * 128 + ((blk ^ (rowa & 7)) * 16));
            }
#pragma unroll
            for (int j = 0; j < 2; ++j) {
                int rowb = wn + j * 16 + r;
                b[j] = *(const bf16x8*)(Bs + rowb * 128 + ((blk ^ (rowb & 7)) * 16));
            }
#pragma unroll
            for (int i = 0; i < 4; ++i)
#pragma unroll
                for (int j = 0; j < 2; ++j)
                    acc[i][j] = __builtin_amdgcn_mfma_f32_16x16x32_bf16(b[j], a[i], acc[i][j], 0, 0, 0);
        }
    }

#pragma unroll
    for (int i = 0; i < 4; ++i) {
        int m = mb + wm + i * 16 + r;
#pragma unroll
        for (int j = 0; j < 2; ++j) {
            int n0 = nb + wn + j * 16 + q4 * 4;
            float4 w;
            w.x = acc[i][j][0] + bvv[j].x;
            w.y = acc[i][j][1] + bvv[j].y;
            w.z = acc[i][j][2] + bvv[j].z;
            w.w = acc[i][j][3] + bvv[j].w;
            *(float4*)(out + (size_t)m * 1024 + n0) = w;
        }
    }
}

// ---------------- causal attention v6: 2 blocks/CU, reg-P ----------------
// 512 blocks x 256 threads (4 waves), 64KB dbuf -> 2 independent blocks/CU:
// when one block sits at its barrier, the other's waves keep the CU busy.
// Balanced qi map: id<256 -> qi=id>>5 (0..7); else 15-((id-256)>>5) (15..8).
// CU-paired blocks (id, id+256) sum to 17 K-tile iterations.
// Per wave: 32 q-rows (2 sets of 16). S^T=K*Q^T keeps P in registers; exp2
// (log2e folded into Q); row-sum via ones-A MFMA. Prefetch after barrier.
__global__ __launch_bounds__(256, 2)
void attn_kernel(const bf16* __restrict__ Q, const bf16* __restrict__ K,
                 const bf16* __restrict__ Vtp, bf16* __restrict__ Aout) {
    __shared__ char lds[65536];
    // buf at 32768*b: K [128 k][64 d] 16KB (128B rows, mask-7 swizzle),
    //                 V at +16384: [64 d][128 kPV] 16KB (256B rows, mask-15)

    const int tid = threadIdx.x, lane = tid & 63, wid = tid >> 6;   // wid 0..3
    const int r = lane & 15, q4 = lane >> 4;
    const int id = blockIdx.x;
    const int qi = (id < 256) ? (id >> 5) : (15 - ((id - 256) >> 5));
    const int bh = id & 31;
    const int b = bh >> 4, h = bh & 15;
    const size_t hb = (size_t)bh * 131072;

    bf16x8 qf[2][2];
#pragma unroll
    for (int i = 0; i < 2; ++i)
#pragma unroll
        for (int ks = 0; ks < 2; ++ks) {
            int row = qi * 128 + wid * 32 + i * 16 + r;
            qf[i][ks] = *(const bf16x8*)(Q + hb + (size_t)row * 64 + ks * 32 + q4 * 8);
        }

    bf16x8 ones;
#pragma unroll
    for (int j = 0; j < 8; ++j) ones[j] = (bf16)1.0f;

    f32x4 o[2][4];          // O^T accum: [q-set][d-subtile], col=q row=d
    f32x4 osum[2];          // ones-MFMA row-sum accum
#pragma unroll
    for (int i = 0; i < 2; ++i) {
        osum[i] = f32x4{0.f, 0.f, 0.f, 0.f};
#pragma unroll
        for (int jd = 0; jd < 4; ++jd) o[i][jd] = f32x4{0.f, 0.f, 0.f, 0.f};
    }

    auto stage = [&](int buf, int kb) {
        char* Kb = lds + buf * 32768;
        char* Vb = Kb + 16384;
#pragma unroll
        for (int pp = 0; pp < 4; ++pp) {
            int s = pp * 256 + tid;
            int row = s >> 3, blk = s & 7;
            g2l16(K + hb + (size_t)(kb + row) * 64 + ((blk ^ (row & 7)) * 8), Kb + s * 16);
        }
#pragma unroll
        for (int pp = 0; pp < 4; ++pp) {
            int s = pp * 256 + tid;
            int row = s >> 4, ch = s & 15;
            g2l16(Vtp + hb + (size_t)row * 2048 + kb + ((ch ^ (row & 15)) * 8), Vb + s * 16);
        }
    };

    stage(0, 0);

    for (int kt = 0; kt <= qi; ++kt) {
        __syncthreads();
        const int cb = kt & 1;
        if (kt < qi) stage(cb ^ 1, (kt + 1) * 128);   // overlaps compute
        const int kb = kt * 128;
        const char* Kb = lds + cb * 32768;
        const char* Vb = Kb + 16384;

        // S^T = K Q^T : 128 keys x 32 q per wave
        f32x4 sc[2][8];
#pragma unroll
        for (int st = 0; st < 8; ++st) {
            int rowk = st * 16 + r;
            bf16x8 ak0 = *(const bf16x8*)(Kb + rowk * 128 + ((q4 ^ (rowk & 7)) * 16));
            bf16x8 ak1 = *(const bf16x8*)(Kb + rowk * 128 + (((4 + q4) ^ (rowk & 7)) * 16));
#pragma unroll
            for (int i = 0; i < 2; ++i) {
                sc[i][st] = __builtin_amdgcn_mfma_f32_16x16x32_bf16(ak0, qf[i][0], f32x4{0.f, 0.f, 0.f, 0.f}, 0, 0, 0);
                sc[i][st] = __builtin_amdgcn_mfma_f32_16x16x32_bf16(ak1, qf[i][1], sc[i][st], 0, 0, 0);
            }
        }

        // mask + exp2 + pack C-regs directly into PV B-fragments
        const bool dia = (kt == qi);                  // wave-uniform
        bf16x8 pb[2][4];
#pragma unroll
        for (int i = 0; i < 2; ++i) {
            int qrow = qi * 128 + wid * 32 + i * 16 + r;
#pragma unroll
            for (int c = 0; c < 4; ++c) {
                bf16x8 t;
                if (dia) {
#pragma unroll
                    for (int j = 0; j < 8; ++j) {
                        int st = 2 * c + (j >> 2), reg = j & 3;
                        int key = kb + st * 16 + q4 * 4 + reg;
                        float sv = (key > qrow) ? -1e30f : sc[i][st][reg];
                        t[j] = (bf16)__builtin_amdgcn_exp2f(sv);
                    }
                } else {
#pragma unroll
                    for (int j = 0; j < 8; ++j) {
                        int st = 2 * c + (j >> 2), reg = j & 3;
                        t[j] = (bf16)__builtin_amdgcn_exp2f(sc[i][st][reg]);
                    }
                }
                pb[i][c] = t;
            }
        }

        // O^T += V^T P ; row-sum += 1^T P  (V fragment reused by both q-sets)
#pragma unroll
        for (int c = 0; c < 4; ++c) {
            int sidx = c * 4 + q4;
            osum[0] = __builtin_amdgcn_mfma_f32_16x16x32_bf16(ones, pb[0][c], osum[0], 0, 0, 0);
            osum[1] = __builtin_amdgcn_mfma_f32_16x16x32_bf16(ones, pb[1][c], osum[1], 0, 0, 0);
#pragma unroll
            for (int dsub = 0; dsub < 4; ++dsub) {
                int rowd = dsub * 16 + r;
                bf16x8 av = *(const bf16x8*)(Vb + rowd * 256 + ((sidx ^ (rowd & 15)) * 16));
                o[0][dsub] = __builtin_amdgcn_mfma_f32_16x16x32_bf16(av, pb[0][c], o[0][dsub], 0, 0, 0);
                o[1][dsub] = __builtin_amdgcn_mfma_f32_16x16x32_bf16(av, pb[1][c], o[1][dsub], 0, 0, 0);
            }
        }
    }

    // epilogue: all osum rows hold colsum(q=r)
#pragma unroll
    for (int i = 0; i < 2; ++i) {
        float inv = 1.f / osum[i][0];
        int q = qi * 128 + wid * 32 + i * 16 + r;
#pragma unroll
        for (int dsub = 0; dsub < 4; ++dsub) {
            bf16x4 w;
#pragma unroll
            for (int reg = 0; reg < 4; ++reg) w[reg] = f2bf(o[i][dsub][reg] * inv);
            *(bf16x4*)(Aout + ((size_t)(b * 2048 + q)) * 1024 + h * 64 + dsub * 16 + q4 * 4) = w;
        }
    }
}

// ---------------- launcher ----------------

extern "C" void kernel_launch(void* const* d_in, const int* in_sizes, int n_in,
                              void* d_out, int out_size, void* d_ws, size_t ws_size,
                              hipStream_t stream) {
    const float* x  = (const float*)d_in[0];
    const float* Wq = (const float*)d_in[1];
    const float* bq = (const float*)d_in[2];
    const float* Wk = (const float*)d_in[3];
    const float* bk = (const float*)d_in[4];
    const float* Wv = (const float*)d_in[5];
    const float* bv = (const float*)d_in[6];
    const float* Wo = (const float*)d_in[7];
    const float* bo = (const float*)d_in[8];
    float* out = (float*)d_out;

    char* ws = (char*)d_ws;
    bf16* xb   = (bf16*)(ws);                     // 8 MB
    bf16* wt   = (bf16*)(ws + 8388608);           // 4 x 2 MB transposed weights (QKV contiguous -> [3072][1024])
    bf16* qkv  = (bf16*)(ws + 16777216);          // 3 x 8 MB  (Q,K,V in [bh][t][d])
    bf16* vtp  = (bf16*)(ws + 41943040);          // 8 MB  V^T PV-permuted [bh][d][t']
    bf16* attn = (bf16*)(ws + 50331648);          // 8 MB  attention out [b*t][c]

    hipLaunchKernelGGL(cast_xw_kernel, dim3(3072), dim3(256), 0, stream,
                       x, xb, Wq, Wk, Wv, Wo, wt);
    hipLaunchKernelGGL(gemm_qkv_kernel, dim3(16, 32), dim3(256), 0, stream,
                       xb, wt, bq, bk, bv, qkv);
    hipLaunchKernelGGL(transpose_v_kernel, dim3(16, 32), dim3(256), 0, stream,
                       qkv + (size_t)2 * 4194304, vtp);
    hipLaunchKernelGGL(attn_kernel, dim3(512), dim3(256), 0, stream,
                       qkv, qkv + 4194304, vtp, attn);
    hipLaunchKernelGGL(gemm_o_kernel, dim3(16, 32), dim3(256), 0, stream,
                       attn, wt + (size_t)3 * 1048576, bo, out);
}

// Round 10
// 170.727 us; speedup vs baseline: 1.0518x; 1.0518x over previous
//
#include <hip/hip_runtime.h>
#include <stdint.h>

// Problem constants
#define T_LEN 2048
#define C_DIM 1024
#define NHEAD 16
#define HDIM  64
#define MTOT  4096   // B*T

typedef __bf16 bf16;
typedef __bf16 bf16x4 __attribute__((ext_vector_type(4)));
typedef __bf16 bf16x8 __attribute__((ext_vector_type(8)));
typedef float  f32x4  __attribute__((ext_vector_type(4)));

__device__ __forceinline__ bf16 f2bf(float f) {
    union { float f; unsigned u; } x; x.f = f;
    unsigned r = x.u + 0x7fffu + ((x.u >> 16) & 1u);
    unsigned short h = (unsigned short)(r >> 16);
    return __builtin_bit_cast(bf16, h);
}

// async 16B/lane global -> LDS DMA (m97 pattern). LDS dest linear in lane id.
__device__ __forceinline__ void g2l16(const void* g, const void* l) {
    __builtin_amdgcn_global_load_lds(
        (const __attribute__((address_space(1))) unsigned int*)(uintptr_t)g,
        (__attribute__((address_space(3))) unsigned int*)(uint32_t)(uintptr_t)l,
        16, 0, 0);
}

// ---------------- merged prep: cast x (blocks 0..2047) + transpose/cast W (2048..3071) ----------------
__global__ void cast_xw_kernel(const float* __restrict__ x, bf16* __restrict__ xb,
                               const float* __restrict__ W0, const float* __restrict__ W1,
                               const float* __restrict__ W2, const float* __restrict__ W3,
                               bf16* __restrict__ wt) {
    __shared__ float tile[64][68];
    const int tid = threadIdx.x;
    const int bid = blockIdx.x;
    if (bid < 2048) {
        int f = bid * 256 + tid;                 // 8 bf16 elems each
        const float4* p = (const float4*)x + (size_t)f * 2;
        float4 a = p[0], b = p[1];
        bf16x8 o;
        o[0] = f2bf(a.x); o[1] = f2bf(a.y); o[2] = f2bf(a.z); o[3] = f2bf(a.w);
        o[4] = f2bf(b.x); o[5] = f2bf(b.y); o[6] = f2bf(b.z); o[7] = f2bf(b.w);
        ((bf16x8*)xb)[f] = o;
        return;
    }
    const int i = bid - 2048;                    // 0..1023
    const int w = i >> 8;
    const int nt = (i >> 4) & 15;
    const int kt = i & 15;
    const float* W = (w == 0) ? W0 : (w == 1) ? W1 : (w == 2) ? W2 : W3;
    const int kb = kt * 64, nb = nt * 64;
#pragma unroll
    for (int pass = 0; pass < 4; ++pass) {
        int row = pass * 16 + (tid >> 4);
        int col = (tid & 15) * 4;
        float4 v = *(const float4*)(W + (size_t)(kb + row) * 1024 + nb + col);
        *(float4*)(&tile[row][col]) = v;
    }
    __syncthreads();
#pragma unroll
    for (int pass = 0; pass < 2; ++pass) {
        int s = pass * 256 + tid;
        int nn = s >> 3, c = s & 7;
        bf16x8 o;
#pragma unroll
        for (int j = 0; j < 8; ++j) o[j] = f2bf(tile[c * 8 + j][nn]);
        *(bf16x8*)(wt + (size_t)w * 1048576 + (size_t)(nb + nn) * 1024 + kb + c * 8) = o;
    }
}

// V[bh][t][d] -> Vtp[bh][d][PV-permuted t]. Within each 32-key chunk,
// PV position matches the S^T C-layout -> PV B-fragment register identity.
__global__ void transpose_v_kernel(const bf16* __restrict__ V, bf16* __restrict__ Vtp) {
    __shared__ bf16 tile[128][72];   // 144B rows (16B-aligned)
    const int tid = threadIdx.x;
    const int t0 = blockIdx.x * 128, bh = blockIdx.y;
    const size_t hb = (size_t)bh * 131072;
#pragma unroll
    for (int pass = 0; pass < 4; ++pass) {
        int s = pass * 256 + tid;
        int row = s >> 3, c = s & 7;             // t-row, d-chunk
        bf16x8 v = *(const bf16x8*)(V + hb + (size_t)(t0 + row) * 64 + c * 8);
        *(bf16x8*)(&tile[row][c * 8]) = v;
    }
    __syncthreads();
#pragma unroll
    for (int pass = 0; pass < 4; ++pass) {
        int s = pass * 256 + tid;
        int d = s >> 4, ch = s & 15;             // out d row, PV-position chunk of 8
        bf16x8 o;
#pragma unroll
        for (int j = 0; j < 8; ++j) {
            int orig = 32 * (ch >> 2) + 16 * (j >> 2) + 4 * (ch & 3) + (j & 3);
            o[j] = tile[orig][d];
        }
        *(bf16x8*)(Vtp + hb + (size_t)d * 2048 + t0 + ch * 8) = o;
    }
}

// ---------------- QKV projection GEMM: 128m x 192n tiles over [3072][1024] B^T ----------------
// (R8 known-good.) 512 blocks = 2/CU, zero tail. Swapped-operand MFMA -> C^T
// layout -> bf16x4 stores. Q region prescaled by 0.125*log2(e) for exp2.
__global__ __launch_bounds__(256, 2)
void gemm_qkv_kernel(const bf16* __restrict__ A, const bf16* __restrict__ Wt,
                     const float* __restrict__ b0, const float* __restrict__ b1,
                     const float* __restrict__ b2, bf16* __restrict__ outQKV) {
    __shared__ char lds[40960];
    bf16* As = (bf16*)lds;            // [128][64] swizzled, mask 7 (16KB)
    bf16* Bs = (bf16*)(lds + 16384);  // [192][64] swizzled, mask 7 (24KB)

    const int tid = threadIdx.x;
    const int lane = tid & 63, wid = tid >> 6;
    const int r = lane & 15, q4 = lane >> 4;
    const int mbase = blockIdx.y * 128;
    const int nbase = blockIdx.x * 192;          // n' in [0,3072)
    const int wm = (wid >> 1) * 64;
    const int wn = (wid & 1) * 96;

    f32x4 acc[4][6];
#pragma unroll
    for (int i = 0; i < 4; ++i)
#pragma unroll
        for (int j = 0; j < 6; ++j) acc[i][j] = f32x4{0.f, 0.f, 0.f, 0.f};

    for (int kt = 0; kt < 16; ++kt) {
        int kb = kt * 64;
#pragma unroll
        for (int p = 0; p < 4; ++p) {
            int s = p * 256 + tid;
            int row = s >> 3, blk = s & 7;
            g2l16(A + (size_t)(mbase + row) * 1024 + kb + ((blk ^ (row & 7)) * 8), (char*)As + s * 16);
        }
#pragma unroll
        for (int p = 0; p < 6; ++p) {
            int s = p * 256 + tid;
            int row = s >> 3, blk = s & 7;
            g2l16(Wt + (size_t)(nbase + row) * 1024 + kb + ((blk ^ (row & 7)) * 8), (char*)Bs + s * 16);
        }
        __syncthreads();
#pragma unroll
        for (int ks = 0; ks < 2; ++ks) {
            int blk = ks * 4 + q4;
            bf16x8 a[4], b[6];
#pragma unroll
            for (int i = 0; i < 4; ++i) {
                int rowa = wm + i * 16 + r;
                a[i] = *(const bf16x8*)((const char*)As + rowa * 128 + ((blk ^ (rowa & 7)) * 16));
            }
#pragma unroll
            for (int j = 0; j < 6; ++j) {
                int rowb = wn + j * 16 + r;
                b[j] = *(const bf16x8*)((const char*)Bs + rowb * 128 + ((blk ^ (rowb & 7)) * 16));
            }
#pragma unroll
            for (int i = 0; i < 4; ++i)
#pragma unroll
                for (int j = 0; j < 6; ++j)
                    acc[i][j] = __builtin_amdgcn_mfma_f32_16x16x32_bf16(b[j], a[i], acc[i][j], 0, 0, 0);
        }
        __syncthreads();
    }

    // C^T epilogue: lane holds 4 consecutive n' for fixed m.
    const float QS = 0.18033688011112042f;       // 0.125 * log2(e)
#pragma unroll
    for (int i = 0; i < 4; ++i) {
        int m = mbase + wm + i * 16 + r;
        int bi = m >> 11, t = m & 2047;
#pragma unroll
        for (int j = 0; j < 6; ++j) {
            int n0 = nbase + wn + j * 16 + q4 * 4;   // global n' in [0,3072)
            int z = n0 >> 10;
            int nz = n0 & 1023;
            const float* bias = (z == 0) ? b0 : (z == 1) ? b1 : b2;
            float4 bb = *(const float4*)(bias + nz);
            float osc = (z == 0) ? QS : 1.0f;
            bf16x4 w;
            w[0] = f2bf((acc[i][j][0] + bb.x) * osc);
            w[1] = f2bf((acc[i][j][1] + bb.y) * osc);
            w[2] = f2bf((acc[i][j][2] + bb.z) * osc);
            w[3] = f2bf((acc[i][j][3] + bb.w) * osc);
            int h = nz >> 6, d = nz & 63;
            *(bf16x4*)(outQKV + (size_t)z * 4194304 + ((size_t)(bi * 16 + h) * 2048 + t) * 64 + d) = w;
        }
    }
}

// ---------------- output projection GEMM: 64m x 64n tiles, 8 blocks/CU ----------------
// 1024 blocks x 128 threads (2 waves) -> 8 blocks/CU: a barrier in one block is
// covered by 7 independent blocks (block-level latency hiding). 16KB LDS each.
__global__ __launch_bounds__(128, 4)
void gemm_o_kernel(const bf16* __restrict__ A, const bf16* __restrict__ Bt,
                   const float* __restrict__ bias, float* __restrict__ out) {
    __shared__ char lds[16384];
    bf16* As = (bf16*)lds;            // [64][64] swizzled mask 7 (8KB)
    bf16* Bs = (bf16*)(lds + 8192);   // [64][64] swizzled mask 7 (8KB)

    const int tid = threadIdx.x;
    const int lane = tid & 63, wid = tid >> 6;   // 0..1
    const int r = lane & 15, q4 = lane >> 4;
    const int nb = blockIdx.x * 64;
    const int mb = blockIdx.y * 64;
    const int wn = wid * 32;

    float4 bvv[2];
#pragma unroll
    for (int j = 0; j < 2; ++j) bvv[j] = *(const float4*)(bias + nb + wn + j * 16 + q4 * 4);

    f32x4 acc[4][2];
#pragma unroll
    for (int i = 0; i < 4; ++i)
#pragma unroll
        for (int j = 0; j < 2; ++j) acc[i][j] = f32x4{0.f, 0.f, 0.f, 0.f};

    for (int kt = 0; kt < 16; ++kt) {
        int kb = kt * 64;
#pragma unroll
        for (int p = 0; p < 4; ++p) {
            int s = p * 128 + tid;
            int row = s >> 3, blk = s & 7;
            g2l16(A + (size_t)(mb + row) * 1024 + kb + ((blk ^ (row & 7)) * 8), (char*)As + s * 16);
        }
#pragma unroll
        for (int p = 0; p < 4; ++p) {
            int s = p * 128 + tid;
            int row = s >> 3, blk = s & 7;
            g2l16(Bt + (size_t)(nb + row) * 1024 + kb + ((blk ^ (row & 7)) * 8), (char*)Bs + s * 16);
        }
        __syncthreads();
#pragma unroll
        for (int ks = 0; ks < 2; ++ks) {
            int blk = ks * 4 + q4;
            bf16x8 a[4], b[2];
#pragma unroll
            for (int i = 0; i < 4; ++i) {
                int rowa = i * 16 + r;
                a[i] = *(const bf16x8*)((const char*)As + rowa * 128 + ((blk ^ (rowa & 7)) * 16));
            }
#pragma unroll
            for (int j = 0; j < 2; ++j) {
                int rowb = wn + j * 16 + r;
                b[j] = *(const bf16x8*)((const char*)Bs + rowb * 128 + ((blk ^ (rowb & 7)) * 16));
            }
#pragma unroll
            for (int i = 0; i < 4; ++i)
#pragma unroll
                for (int j = 0; j < 2; ++j)
                    acc[i][j] = __builtin_amdgcn_mfma_f32_16x16x32_bf16(b[j], a[i], acc[i][j], 0, 0, 0);
        }
        __syncthreads();
    }

#pragma unroll
    for (int i = 0; i < 4; ++i) {
        int m = mb + i * 16 + r;
#pragma unroll
        for (int j = 0; j < 2; ++j) {
            int n0 = nb + wn + j * 16 + q4 * 4;
            float4 w;
            w.x = acc[i][j][0] + bvv[j].x;
            w.y = acc[i][j][1] + bvv[j].y;
            w.z = acc[i][j][2] + bvv[j].z;
            w.w = acc[i][j][3] + bvv[j].w;
            *(float4*)(out + (size_t)m * 1024 + n0) = w;
        }
    }
}

// ---------------- causal attention v5 (R8 known-good): merged q-pair, 8 waves, reg-P ----------------
// 256 blocks x 512 threads (2 waves/SIMD). Block p handles q-tiles qiA=p and
// qiB=15-p in ONE K-tile stream kt=0..15-p (shared-prefix tiles loaded once).
// S^T=K*Q^T keeps P in registers; exp2 (log2e pre-folded into Q); row-sum via
// ones-A MFMA on packed P. K/V double-buffered 64KB, 1 barrier/tile.
__global__ __launch_bounds__(512, 2)
void attn_kernel(const bf16* __restrict__ Q, const bf16* __restrict__ K,
                 const bf16* __restrict__ Vtp, bf16* __restrict__ Aout) {
    __shared__ char lds[65536];
    // K bufs: [128 k][64 d] 128B rows, slot^(row&7), at 0 / 16384      (2x16KB)
    // V bufs: [64 d][128 kPV] 256B rows, slot^(d&15), at 32768 / 49152 (2x16KB)

    const int tid = threadIdx.x, lane = tid & 63, wid = tid >> 6;   // wid 0..7
    const int r = lane & 15, q4 = lane >> 4;
    const int p = blockIdx.x >> 5;          // 0..7
    const int bh = blockIdx.x & 31;
    const int b = bh >> 4, h = bh & 15;
    const size_t hb = (size_t)bh * 131072;

    const int qi[2] = { p, 15 - p };        // A, B 128-row q-tiles
    const int ittot = 16 - p;               // kt = 0..15-p

    bf16x8 qf[2][2];
#pragma unroll
    for (int i = 0; i < 2; ++i)
#pragma unroll
        for (int ks = 0; ks < 2; ++ks) {
            int row = qi[i] * 128 + wid * 16 + r;
            qf[i][ks] = *(const bf16x8*)(Q + hb + (size_t)row * 64 + ks * 32 + q4 * 8);
        }

    bf16x8 ones;
#pragma unroll
    for (int j = 0; j < 8; ++j) ones[j] = (bf16)1.0f;

    f32x4 o[2][4];          // O^T accum: [q-tile][d-subtile], col=q row=d
    f32x4 osum[2];          // ones-MFMA row-sum accum (all rows = colsum)
#pragma unroll
    for (int i = 0; i < 2; ++i) {
        osum[i] = f32x4{0.f, 0.f, 0.f, 0.f};
#pragma unroll
        for (int jd = 0; jd < 4; ++jd) o[i][jd] = f32x4{0.f, 0.f, 0.f, 0.f};
    }

    auto stage = [&](int buf, int kb) {
        char* Kb = lds + buf * 16384;
        char* Vb = lds + 32768 + buf * 16384;
#pragma unroll
        for (int pp = 0; pp < 2; ++pp) {
            int s = pp * 512 + tid;
            int row = s >> 3, blk = s & 7;
            g2l16(K + hb + (size_t)(kb + row) * 64 + ((blk ^ (row & 7)) * 8), Kb + s * 16);
        }
#pragma unroll
        for (int pp = 0; pp < 2; ++pp) {
            int s = pp * 512 + tid;
            int row = s >> 4, ch = s & 15;
            g2l16(Vtp + hb + (size_t)row * 2048 + kb + ((ch ^ (row & 15)) * 8), Vb + s * 16);
        }
    };

    stage(0, 0);

    for (int it = 0; it < ittot; ++it) {
        __syncthreads();
        const int cb = it & 1;
        if (it + 1 < ittot) stage((it + 1) & 1, (it + 1) * 128);   // overlaps compute
        const int kb = it * 128;
        const char* Kb = lds + cb * 16384;
        const char* Vb = lds + 32768 + cb * 16384;
        const bool aAct = (it <= qi[0]);    // wave-uniform

        // S^T = K Q^T : 128 keys x (16 A-q if active) + 16 B-q
        f32x4 sc[2][8];
#pragma unroll
        for (int st = 0; st < 8; ++st) {
            int rowk = st * 16 + r;
            bf16x8 ak0 = *(const bf16x8*)(Kb + rowk * 128 + ((q4 ^ (rowk & 7)) * 16));
            bf16x8 ak1 = *(const bf16x8*)(Kb + rowk * 128 + (((4 + q4) ^ (rowk & 7)) * 16));
            sc[1][st] = __builtin_amdgcn_mfma_f32_16x16x32_bf16(ak0, qf[1][0], f32x4{0.f, 0.f, 0.f, 0.f}, 0, 0, 0);
            sc[1][st] = __builtin_amdgcn_mfma_f32_16x16x32_bf16(ak1, qf[1][1], sc[1][st], 0, 0, 0);
            if (aAct) {
                sc[0][st] = __builtin_amdgcn_mfma_f32_16x16x32_bf16(ak0, qf[0][0], f32x4{0.f, 0.f, 0.f, 0.f}, 0, 0, 0);
                sc[0][st] = __builtin_amdgcn_mfma_f32_16x16x32_bf16(ak1, qf[0][1], sc[0][st], 0, 0, 0);
            }
        }

        // mask + exp2 + pack C-regs directly into PV B-fragments; sum via ones-MFMA
#pragma unroll
        for (int i = 0; i < 2; ++i) {
            if (i == 0 && !aAct) continue;
            const bool dia = (it == qi[i]);             // wave-uniform
            int qrow = qi[i] * 128 + wid * 16 + r;
            bf16x8 pb[4];
#pragma unroll
            for (int c = 0; c < 4; ++c) {
                bf16x8 t;
                if (dia) {
#pragma unroll
                    for (int j = 0; j < 8; ++j) {
                        int st = 2 * c + (j >> 2), reg = j & 3;
                        int key = kb + st * 16 + q4 * 4 + reg;
                        float sv = (key > qrow) ? -1e30f : sc[i][st][reg];
                        t[j] = (bf16)__builtin_amdgcn_exp2f(sv);
                    }
                } else {
#pragma unroll
                    for (int j = 0; j < 8; ++j) {
                        int st = 2 * c + (j >> 2), reg = j & 3;
                        t[j] = (bf16)__builtin_amdgcn_exp2f(sc[i][st][reg]);
                    }
                }
                pb[c] = t;
            }
            // O^T += V^T P ; row-sum += 1^T P
#pragma unroll
            for (int c = 0; c < 4; ++c) {
                int sidx = c * 4 + q4;
                osum[i] = __builtin_amdgcn_mfma_f32_16x16x32_bf16(ones, pb[c], osum[i], 0, 0, 0);
#pragma unroll
                for (int dsub = 0; dsub < 4; ++dsub) {
                    int rowd = dsub * 16 + r;
                    bf16x8 av = *(const bf16x8*)(Vb + rowd * 256 + ((sidx ^ (rowd & 15)) * 16));
                    o[i][dsub] = __builtin_amdgcn_mfma_f32_16x16x32_bf16(av, pb[c], o[i][dsub], 0, 0, 0);
                }
            }
        }
    }

    // epilogue: all osum rows hold colsum(q=r)
#pragma unroll
    for (int i = 0; i < 2; ++i) {
        float inv = 1.f / osum[i][0];
        int q = qi[i] * 128 + wid * 16 + r;
#pragma unroll
        for (int dsub = 0; dsub < 4; ++dsub) {
            bf16x4 w;
#pragma unroll
            for (int reg = 0; reg < 4; ++reg) w[reg] = f2bf(o[i][dsub][reg] * inv);
            *(bf16x4*)(Aout + ((size_t)(b * 2048 + q)) * 1024 + h * 64 + dsub * 16 + q4 * 4) = w;
        }
    }
}

// ---------------- launcher ----------------

extern "C" void kernel_launch(void* const* d_in, const int* in_sizes, int n_in,
                              void* d_out, int out_size, void* d_ws, size_t ws_size,
                              hipStream_t stream) {
    const float* x  = (const float*)d_in[0];
    const float* Wq = (const float*)d_in[1];
    const float* bq = (const float*)d_in[2];
    const float* Wk = (const float*)d_in[3];
    const float* bk = (const float*)d_in[4];
    const float* Wv = (const float*)d_in[5];
    const float* bv = (const float*)d_in[6];
    const float* Wo = (const float*)d_in[7];
    const float* bo = (const float*)d_in[8];
    float* out = (float*)d_out;

    char* ws = (char*)d_ws;
    bf16* xb   = (bf16*)(ws);                     // 8 MB
    bf16* wt   = (bf16*)(ws + 8388608);           // 4 x 2 MB transposed weights (QKV contiguous -> [3072][1024])
    bf16* qkv  = (bf16*)(ws + 16777216);          // 3 x 8 MB  (Q,K,V in [bh][t][d])
    bf16* vtp  = (bf16*)(ws + 41943040);          // 8 MB  V^T PV-permuted [bh][d][t']
    bf16* attn = (bf16*)(ws + 50331648);          // 8 MB  attention out [b*t][c]

    hipLaunchKernelGGL(cast_xw_kernel, dim3(3072), dim3(256), 0, stream,
                       x, xb, Wq, Wk, Wv, Wo, wt);
    hipLaunchKernelGGL(gemm_qkv_kernel, dim3(16, 32), dim3(256), 0, stream,
                       xb, wt, bq, bk, bv, qkv);
    hipLaunchKernelGGL(transpose_v_kernel, dim3(16, 32), dim3(256), 0, stream,
                       qkv + (size_t)2 * 4194304, vtp);
    hipLaunchKernelGGL(attn_kernel, dim3(256), dim3(512), 0, stream,
                       qkv, qkv + 4194304, vtp, attn);
    hipLaunchKernelGGL(gemm_o_kernel, dim3(16, 64), dim3(128), 0, stream,
                       attn, wt + (size_t)3 * 1048576, bo, out);
}

// Round 11
// 170.163 us; speedup vs baseline: 1.0553x; 1.0033x over previous
//
#include <hip/hip_runtime.h>
#include <stdint.h>

// Problem constants
#define T_LEN 2048
#define C_DIM 1024
#define NHEAD 16
#define HDIM  64
#define MTOT  4096   // B*T

typedef __bf16 bf16;
typedef __bf16 bf16x4 __attribute__((ext_vector_type(4)));
typedef __bf16 bf16x8 __attribute__((ext_vector_type(8)));
typedef float  f32x4  __attribute__((ext_vector_type(4)));

__device__ __forceinline__ bf16 f2bf(float f) {
    union { float f; unsigned u; } x; x.f = f;
    unsigned r = x.u + 0x7fffu + ((x.u >> 16) & 1u);
    unsigned short h = (unsigned short)(r >> 16);
    return __builtin_bit_cast(bf16, h);
}

// async 16B/lane global -> LDS DMA (m97 pattern). LDS dest linear in lane id.
__device__ __forceinline__ void g2l16(const void* g, const void* l) {
    __builtin_amdgcn_global_load_lds(
        (const __attribute__((address_space(1))) unsigned int*)(uintptr_t)g,
        (__attribute__((address_space(3))) unsigned int*)(uint32_t)(uintptr_t)l,
        16, 0, 0);
}

// ---------------- merged prep: cast x (blocks 0..2047) + transpose/cast W (2048..3071) ----------------
__global__ void cast_xw_kernel(const float* __restrict__ x, bf16* __restrict__ xb,
                               const float* __restrict__ W0, const float* __restrict__ W1,
                               const float* __restrict__ W2, const float* __restrict__ W3,
                               bf16* __restrict__ wt) {
    __shared__ float tile[64][68];
    const int tid = threadIdx.x;
    const int bid = blockIdx.x;
    if (bid < 2048) {
        int f = bid * 256 + tid;                 // 8 bf16 elems each
        const float4* p = (const float4*)x + (size_t)f * 2;
        float4 a = p[0], b = p[1];
        bf16x8 o;
        o[0] = f2bf(a.x); o[1] = f2bf(a.y); o[2] = f2bf(a.z); o[3] = f2bf(a.w);
        o[4] = f2bf(b.x); o[5] = f2bf(b.y); o[6] = f2bf(b.z); o[7] = f2bf(b.w);
        ((bf16x8*)xb)[f] = o;
        return;
    }
    const int i = bid - 2048;                    // 0..1023
    const int w = i >> 8;
    const int nt = (i >> 4) & 15;
    const int kt = i & 15;
    const float* W = (w == 0) ? W0 : (w == 1) ? W1 : (w == 2) ? W2 : W3;
    const int kb = kt * 64, nb = nt * 64;
#pragma unroll
    for (int pass = 0; pass < 4; ++pass) {
        int row = pass * 16 + (tid >> 4);
        int col = (tid & 15) * 4;
        float4 v = *(const float4*)(W + (size_t)(kb + row) * 1024 + nb + col);
        *(float4*)(&tile[row][col]) = v;
    }
    __syncthreads();
#pragma unroll
    for (int pass = 0; pass < 2; ++pass) {
        int s = pass * 256 + tid;
        int nn = s >> 3, c = s & 7;
        bf16x8 o;
#pragma unroll
        for (int j = 0; j < 8; ++j) o[j] = f2bf(tile[c * 8 + j][nn]);
        *(bf16x8*)(wt + (size_t)w * 1048576 + (size_t)(nb + nn) * 1024 + kb + c * 8) = o;
    }
}

// ---------------- QKV projection GEMM: 128m x 192n tiles over [3072][1024] B^T ----------------
// 512 blocks = 2/CU, zero tail. Swapped-operand MFMA -> C^T layout -> bf16x4
// stores. Q region prescaled by 0.125*log2(e) for exp2. V region (z==2) is
// written DIRECTLY into Vtp[bh][d][t'] with the PV permutation
// t' = (t&96) | ((t>>2)&3)<<3 | ((t>>4)&1)<<2 | (t&3)  (t tile-local 0..127),
// eliminating the separate transpose kernel.
__global__ __launch_bounds__(256, 2)
void gemm_qkv_kernel(const bf16* __restrict__ A, const bf16* __restrict__ Wt,
                     const float* __restrict__ b0, const float* __restrict__ b1,
                     const float* __restrict__ b2, bf16* __restrict__ outQKV,
                     bf16* __restrict__ Vtp) {
    __shared__ char lds[40960];
    bf16* As = (bf16*)lds;            // [128][64] swizzled, mask 7 (16KB)
    bf16* Bs = (bf16*)(lds + 16384);  // [192][64] swizzled, mask 7 (24KB)

    const int tid = threadIdx.x;
    const int lane = tid & 63, wid = tid >> 6;
    const int r = lane & 15, q4 = lane >> 4;
    const int mbase = blockIdx.y * 128;
    const int nbase = blockIdx.x * 192;          // n' in [0,3072)
    const int wm = (wid >> 1) * 64;
    const int wn = (wid & 1) * 96;

    f32x4 acc[4][6];
#pragma unroll
    for (int i = 0; i < 4; ++i)
#pragma unroll
        for (int j = 0; j < 6; ++j) acc[i][j] = f32x4{0.f, 0.f, 0.f, 0.f};

    for (int kt = 0; kt < 16; ++kt) {
        int kb = kt * 64;
#pragma unroll
        for (int p = 0; p < 4; ++p) {
            int s = p * 256 + tid;
            int row = s >> 3, blk = s & 7;
            g2l16(A + (size_t)(mbase + row) * 1024 + kb + ((blk ^ (row & 7)) * 8), (char*)As + s * 16);
        }
#pragma unroll
        for (int p = 0; p < 6; ++p) {
            int s = p * 256 + tid;
            int row = s >> 3, blk = s & 7;
            g2l16(Wt + (size_t)(nbase + row) * 1024 + kb + ((blk ^ (row & 7)) * 8), (char*)Bs + s * 16);
        }
        __syncthreads();
#pragma unroll
        for (int ks = 0; ks < 2; ++ks) {
            int blk = ks * 4 + q4;
            bf16x8 a[4], b[6];
#pragma unroll
            for (int i = 0; i < 4; ++i) {
                int rowa = wm + i * 16 + r;
                a[i] = *(const bf16x8*)((const char*)As + rowa * 128 + ((blk ^ (rowa & 7)) * 16));
            }
#pragma unroll
            for (int j = 0; j < 6; ++j) {
                int rowb = wn + j * 16 + r;
                b[j] = *(const bf16x8*)((const char*)Bs + rowb * 128 + ((blk ^ (rowb & 7)) * 16));
            }
#pragma unroll
            for (int i = 0; i < 4; ++i)
#pragma unroll
                for (int j = 0; j < 6; ++j)
                    acc[i][j] = __builtin_amdgcn_mfma_f32_16x16x32_bf16(b[j], a[i], acc[i][j], 0, 0, 0);
        }
        __syncthreads();
    }

    // C^T epilogue: lane holds 4 consecutive n' for fixed m.
    const float QS = 0.18033688011112042f;       // 0.125 * log2(e)
#pragma unroll
    for (int i = 0; i < 4; ++i) {
        int m = mbase + wm + i * 16 + r;
        int bi = m >> 11, t = m & 2047;
#pragma unroll
        for (int j = 0; j < 6; ++j) {
            int n0 = nbase + wn + j * 16 + q4 * 4;   // global n' in [0,3072)
            int z = n0 >> 10;
            int nz = n0 & 1023;
            const float* bias = (z == 0) ? b0 : (z == 1) ? b1 : b2;
            float4 bb = *(const float4*)(bias + nz);
            int h = nz >> 6, d = nz & 63;
            if (z == 2) {
                // V: scatter into Vtp[bh][d][t'] (PV-permuted within 128-tiles)
                int tl = t & 127;
                int tp = (tl & 96) | (((tl >> 2) & 3) << 3) | (((tl >> 4) & 1) << 2) | (tl & 3);
                size_t base = (size_t)(bi * 16 + h) * 131072 + (size_t)(t & ~127) + tp;
                Vtp[base + (size_t)(d + 0) * 2048] = f2bf(acc[i][j][0] + bb.x);
                Vtp[base + (size_t)(d + 1) * 2048] = f2bf(acc[i][j][1] + bb.y);
                Vtp[base + (size_t)(d + 2) * 2048] = f2bf(acc[i][j][2] + bb.z);
                Vtp[base + (size_t)(d + 3) * 2048] = f2bf(acc[i][j][3] + bb.w);
            } else {
                float osc = (z == 0) ? QS : 1.0f;
                bf16x4 w;
                w[0] = f2bf((acc[i][j][0] + bb.x) * osc);
                w[1] = f2bf((acc[i][j][1] + bb.y) * osc);
                w[2] = f2bf((acc[i][j][2] + bb.z) * osc);
                w[3] = f2bf((acc[i][j][3] + bb.w) * osc);
                *(bf16x4*)(outQKV + (size_t)z * 4194304 + ((size_t)(bi * 16 + h) * 2048 + t) * 64 + d) = w;
            }
        }
    }
}

// ---------------- output projection GEMM: 64m x 64n tiles, 8 blocks/CU ----------------
__global__ __launch_bounds__(128, 4)
void gemm_o_kernel(const bf16* __restrict__ A, const bf16* __restrict__ Bt,
                   const float* __restrict__ bias, float* __restrict__ out) {
    __shared__ char lds[16384];
    bf16* As = (bf16*)lds;            // [64][64] swizzled mask 7 (8KB)
    bf16* Bs = (bf16*)(lds + 8192);   // [64][64] swizzled mask 7 (8KB)

    const int tid = threadIdx.x;
    const int lane = tid & 63, wid = tid >> 6;   // 0..1
    const int r = lane & 15, q4 = lane >> 4;
    const int nb = blockIdx.x * 64;
    const int mb = blockIdx.y * 64;
    const int wn = wid * 32;

    float4 bvv[2];
#pragma unroll
    for (int j = 0; j < 2; ++j) bvv[j] = *(const float4*)(bias + nb + wn + j * 16 + q4 * 4);

    f32x4 acc[4][2];
#pragma unroll
    for (int i = 0; i < 4; ++i)
#pragma unroll
        for (int j = 0; j < 2; ++j) acc[i][j] = f32x4{0.f, 0.f, 0.f, 0.f};

    for (int kt = 0; kt < 16; ++kt) {
        int kb = kt * 64;
#pragma unroll
        for (int p = 0; p < 4; ++p) {
            int s = p * 128 + tid;
            int row = s >> 3, blk = s & 7;
            g2l16(A + (size_t)(mb + row) * 1024 + kb + ((blk ^ (row & 7)) * 8), (char*)As + s * 16);
        }
#pragma unroll
        for (int p = 0; p < 4; ++p) {
            int s = p * 128 + tid;
            int row = s >> 3, blk = s & 7;
            g2l16(Bt + (size_t)(nb + row) * 1024 + kb + ((blk ^ (row & 7)) * 8), (char*)Bs + s * 16);
        }
        __syncthreads();
#pragma unroll
        for (int ks = 0; ks < 2; ++ks) {
            int blk = ks * 4 + q4;
            bf16x8 a[4], b[2];
#pragma unroll
            for (int i = 0; i < 4; ++i) {
                int rowa = i * 16 + r;
                a[i] = *(const bf16x8*)((const char*)As + rowa * 128 + ((blk ^ (rowa & 7)) * 16));
            }
#pragma unroll
            for (int j = 0; j < 2; ++j) {
                int rowb = wn + j * 16 + r;
                b[j] = *(const bf16x8*)((const char*)Bs + rowb * 128 + ((blk ^ (rowb & 7)) * 16));
            }
#pragma unroll
            for (int i = 0; i < 4; ++i)
#pragma unroll
                for (int j = 0; j < 2; ++j)
                    acc[i][j] = __builtin_amdgcn_mfma_f32_16x16x32_bf16(b[j], a[i], acc[i][j], 0, 0, 0);
        }
        __syncthreads();
    }

#pragma unroll
    for (int i = 0; i < 4; ++i) {
        int m = mb + i * 16 + r;
#pragma unroll
        for (int j = 0; j < 2; ++j) {
            int n0 = nb + wn + j * 16 + q4 * 4;
            float4 w;
            w.x = acc[i][j][0] + bvv[j].x;
            w.y = acc[i][j][1] + bvv[j].y;
            w.z = acc[i][j][2] + bvv[j].z;
            w.w = acc[i][j][3] + bvv[j].w;
            *(float4*)(out + (size_t)m * 1024 + n0) = w;
        }
    }
}

// ---------------- causal attention v7: 64-key tiles, uniform folded pairs, 2 blocks/CU ----------------
// 512 blocks x 256 threads (4 waves). Block (p, bh), p in 0..15: 64-row q-tiles
// qiA=p, qiB=31-p in ONE 64-key K-tile stream it=0..31-p; A active while it<=p
// -> exactly 33 tile-computations per block (uniform duration, unlike R9 v6).
// 2 independent blocks/CU (2 x 16KB dbuf = 64KB) hide each other's barriers.
// S^T=K*Q^T keeps P in registers; exp2 (log2e folded into Q); row-sum via
// ones-A MFMA; normalization at epilogue. Prefetch issued after the barrier.
__global__ __launch_bounds__(256, 2)
void attn_kernel(const bf16* __restrict__ Q, const bf16* __restrict__ K,
                 const bf16* __restrict__ Vtp, bf16* __restrict__ Aout) {
    __shared__ char lds[32768];
    // buf at 16384*b: K [64 k][64 d] 8KB + V [64 d][64 k'] 8KB (128B rows, mask-7)

    const int tid = threadIdx.x, lane = tid & 63, wid = tid >> 6;   // wid 0..3
    const int r = lane & 15, q4 = lane >> 4;
    const int p = blockIdx.x >> 5;          // 0..15
    const int bh = blockIdx.x & 31;
    const int b = bh >> 4, h = bh & 15;
    const size_t hb = (size_t)bh * 131072;

    const int qi[2] = { p, 31 - p };        // 64-row q-tiles
    const int ittot = 32 - p;               // 64-key K-tiles 0..31-p

    bf16x8 qf[2][2];
#pragma unroll
    for (int i = 0; i < 2; ++i)
#pragma unroll
        for (int ks = 0; ks < 2; ++ks) {
            int row = qi[i] * 64 + wid * 16 + r;
            qf[i][ks] = *(const bf16x8*)(Q + hb + (size_t)row * 64 + ks * 32 + q4 * 8);
        }

    bf16x8 ones;
#pragma unroll
    for (int j = 0; j < 8; ++j) ones[j] = (bf16)1.0f;

    f32x4 o[2][4];          // O^T accum: [q-tile][d-subtile], col=q row=d
    f32x4 osum[2];          // ones-MFMA row-sum accum
#pragma unroll
    for (int i = 0; i < 2; ++i) {
        osum[i] = f32x4{0.f, 0.f, 0.f, 0.f};
#pragma unroll
        for (int jd = 0; jd < 4; ++jd) o[i][jd] = f32x4{0.f, 0.f, 0.f, 0.f};
    }

    auto stage = [&](int buf, int kb) {
        char* Kb = lds + buf * 16384;
        char* Vb = Kb + 8192;
#pragma unroll
        for (int pp = 0; pp < 2; ++pp) {
            int s = pp * 256 + tid;
            int row = s >> 3, blk = s & 7;
            g2l16(K + hb + (size_t)(kb + row) * 64 + ((blk ^ (row & 7)) * 8), Kb + s * 16);
        }
#pragma unroll
        for (int pp = 0; pp < 2; ++pp) {
            int s = pp * 256 + tid;
            int row = s >> 3, ch = s & 7;
            g2l16(Vtp + hb + (size_t)row * 2048 + kb + ((ch ^ (row & 7)) * 8), Vb + s * 16);
        }
    };

    stage(0, 0);

    for (int it = 0; it < ittot; ++it) {
        __syncthreads();
        const int cb = it & 1;
        if (it + 1 < ittot) stage(cb ^ 1, (it + 1) * 64);   // overlaps compute
        const int kb = it * 64;
        const char* Kb = lds + cb * 16384;
        const char* Vb = Kb + 8192;
        const bool aAct = (it <= qi[0]);    // wave-uniform

        // S^T = K Q^T : 64 keys x 16 q per active tile
        f32x4 sc[2][4];
#pragma unroll
        for (int st = 0; st < 4; ++st) {
            int rowk = st * 16 + r;
            bf16x8 ak0 = *(const bf16x8*)(Kb + rowk * 128 + ((q4 ^ (rowk & 7)) * 16));
            bf16x8 ak1 = *(const bf16x8*)(Kb + rowk * 128 + (((4 + q4) ^ (rowk & 7)) * 16));
            sc[1][st] = __builtin_amdgcn_mfma_f32_16x16x32_bf16(ak0, qf[1][0], f32x4{0.f, 0.f, 0.f, 0.f}, 0, 0, 0);
            sc[1][st] = __builtin_amdgcn_mfma_f32_16x16x32_bf16(ak1, qf[1][1], sc[1][st], 0, 0, 0);
            if (aAct) {
                sc[0][st] = __builtin_amdgcn_mfma_f32_16x16x32_bf16(ak0, qf[0][0], f32x4{0.f, 0.f, 0.f, 0.f}, 0, 0, 0);
                sc[0][st] = __builtin_amdgcn_mfma_f32_16x16x32_bf16(ak1, qf[0][1], sc[0][st], 0, 0, 0);
            }
        }

        // mask + exp2 + pack into PV B-fragments; O^T += V^T P; rowsum += 1^T P
#pragma unroll
        for (int i = 0; i < 2; ++i) {
            if (i == 0 && !aAct) continue;
            const bool dia = (it == qi[i]);             // wave-uniform
            int qrow = qi[i] * 64 + wid * 16 + r;
            bf16x8 pb[2];
#pragma unroll
            for (int c = 0; c < 2; ++c) {
                bf16x8 t;
                if (dia) {
#pragma unroll
                    for (int j = 0; j < 8; ++j) {
                        int st = 2 * c + (j >> 2), reg = j & 3;
                        int key = kb + st * 16 + q4 * 4 + reg;
                        float sv = (key > qrow) ? -1e30f : sc[i][st][reg];
                        t[j] = (bf16)__builtin_amdgcn_exp2f(sv);
                    }
                } else {
#pragma unroll
                    for (int j = 0; j < 8; ++j) {
                        int st = 2 * c + (j >> 2), reg = j & 3;
                        t[j] = (bf16)__builtin_amdgcn_exp2f(sc[i][st][reg]);
                    }
                }
                pb[c] = t;
            }
#pragma unroll
            for (int c = 0; c < 2; ++c) {
                int sidx = c * 4 + q4;
                osum[i] = __builtin_amdgcn_mfma_f32_16x16x32_bf16(ones, pb[c], osum[i], 0, 0, 0);
#pragma unroll
                for (int dsub = 0; dsub < 4; ++dsub) {
                    int rowd = dsub * 16 + r;
                    bf16x8 av = *(const bf16x8*)(Vb + rowd * 128 + ((sidx ^ (rowd & 7)) * 16));
                    o[i][dsub] = __builtin_amdgcn_mfma_f32_16x16x32_bf16(av, pb[c], o[i][dsub], 0, 0, 0);
                }
            }
        }
    }

    // epilogue: all osum rows hold colsum(q=r)
#pragma unroll
    for (int i = 0; i < 2; ++i) {
        float inv = 1.f / osum[i][0];
        int q = qi[i] * 64 + wid * 16 + r;
#pragma unroll
        for (int dsub = 0; dsub < 4; ++dsub) {
            bf16x4 w;
#pragma unroll
            for (int reg = 0; reg < 4; ++reg) w[reg] = f2bf(o[i][dsub][reg] * inv);
            *(bf16x4*)(Aout + ((size_t)(b * 2048 + q)) * 1024 + h * 64 + dsub * 16 + q4 * 4) = w;
        }
    }
}

// ---------------- launcher ----------------

extern "C" void kernel_launch(void* const* d_in, const int* in_sizes, int n_in,
                              void* d_out, int out_size, void* d_ws, size_t ws_size,
                              hipStream_t stream) {
    const float* x  = (const float*)d_in[0];
    const float* Wq = (const float*)d_in[1];
    const float* bq = (const float*)d_in[2];
    const float* Wk = (const float*)d_in[3];
    const float* bk = (const float*)d_in[4];
    const float* Wv = (const float*)d_in[5];
    const float* bv = (const float*)d_in[6];
    const float* Wo = (const float*)d_in[7];
    const float* bo = (const float*)d_in[8];
    float* out = (float*)d_out;

    char* ws = (char*)d_ws;
    bf16* xb   = (bf16*)(ws);                     // 8 MB
    bf16* wt   = (bf16*)(ws + 8388608);           // 4 x 2 MB transposed weights (QKV contiguous -> [3072][1024])
    bf16* qkv  = (bf16*)(ws + 16777216);          // Q,K in [bh][t][d] (V slot unused)
    bf16* vtp  = (bf16*)(ws + 41943040);          // 8 MB  V^T PV-permuted [bh][d][t'] (written by gemm_qkv)
    bf16* attn = (bf16*)(ws + 50331648);          // 8 MB  attention out [b*t][c]

    hipLaunchKernelGGL(cast_xw_kernel, dim3(3072), dim3(256), 0, stream,
                       x, xb, Wq, Wk, Wv, Wo, wt);
    hipLaunchKernelGGL(gemm_qkv_kernel, dim3(16, 32), dim3(256), 0, stream,
                       xb, wt, bq, bk, bv, qkv, vtp);
    hipLaunchKernelGGL(attn_kernel, dim3(512), dim3(256), 0, stream,
                       qkv, qkv + 4194304, vtp, attn);
    hipLaunchKernelGGL(gemm_o_kernel, dim3(16, 64), dim3(128), 0, stream,
                       attn, wt + (size_t)3 * 1048576, bo, out);
}